// Round 18
// baseline (154.822 us; speedup 1.0000x reference)
//
#include <hip/hip_runtime.h>
#include <stdint.h>

#define NTOK 197
#define HD 64
#define NH 12
#define CDIM 768
#define BB 64
#define MTOT (BB*NTOK)      /* 12608 */
#define MPAD 12672          /* 99*128 */
#define SCALE 0.125f
#define BTP 208             /* biasT padded dim */

typedef __attribute__((ext_vector_type(8))) short short8;
typedef __attribute__((ext_vector_type(4))) float f32x4;
typedef unsigned short us;

__device__ __forceinline__ us f2b(float f){
    union { float f; uint32_t u; } v; v.f = f;
    uint32_t u = v.u;
    uint32_t r = u + 0x7fffu + ((u >> 16) & 1u);
    return (us)(r >> 16);
}

__device__ __forceinline__ float b2f(us b){
    union { uint32_t u; float f; } v; v.u = ((uint32_t)b) << 16;
    return v.f;
}

__device__ __forceinline__ void gload16(const us* g, us* l){
    __builtin_amdgcn_global_load_lds((const __attribute__((address_space(1))) void*)g,
                                     (__attribute__((address_space(3))) void*)l, 16, 0, 0);
}

#define LGKM0_BAR() do{ asm volatile("s_waitcnt lgkmcnt(0)" ::: "memory"); \
                        __builtin_amdgcn_s_barrier(); }while(0)

// ---------------- fused prep (identical to R14) ----------------
__device__ __forceinline__ void cvt4(const float* in, us* out, int i){
    float4 v = ((const float4*)in)[i];
    ushort4 o;
    o.x = f2b(v.x); o.y = f2b(v.y); o.z = f2b(v.z); o.w = f2b(v.w);
    ((ushort4*)out)[i] = o;
}

__global__ void prep_kernel(const float* __restrict__ x, const float* __restrict__ qkv_w,
                            const float* __restrict__ proj_w,
                            const int* __restrict__ rel_index, const float* __restrict__ rel_table,
                            us* __restrict__ xb, us* __restrict__ wqkv, us* __restrict__ wproj,
                            float* __restrict__ biasT)
{
    const int N1 = MTOT*CDIM/4;
    const int N2 = 3*CDIM*CDIM/4;
    const int N3 = CDIM*CDIM/4;
    const int N4 = BTP*BTP;
    const int total = N1+N2+N3+N4;
    for (int i = blockIdx.x*blockDim.x + threadIdx.x; i < total; i += gridDim.x*blockDim.x){
        if (i < N1) cvt4(x, xb, i);
        else if (i < N1+N2) cvt4(qkv_w, wqkv, i-N1);
        else if (i < N1+N2+N3) cvt4(proj_w, wproj, i-N1-N2);
        else {
            int t = i - N1 - N2 - N3;
            int col = t / BTP, row = t - col*BTP;
            if (row < NTOK && col < NTOK){
                int idx = rel_index[row*NTOK + col];
                #pragma unroll
                for (int h = 0; h < NH; ++h)
                    biasT[((size_t)h*BTP + col)*BTP + row] = rel_table[idx*NH + h];
            } else {
                #pragma unroll
                for (int h = 0; h < NH; ++h)
                    biasT[((size_t)h*BTP + col)*BTP + row] = 0.f;
            }
        }
    }
}

// ====== pgemm6: persistent 8-wave GEMM, BM=128, BN=256, BK=32, 3-buffer rotation,
//        single barrier/step, counted vmcnt(3), 72KB LDS -> 2 blocks/CU.
//        EPI==0: Q/K/V scatter epilogue.  EPI==1: fp32 out + bias (proj). ======
template<int EPI>
__global__ __launch_bounds__(512,2) void pgemm6_kernel(
    const us* __restrict__ A, const us* __restrict__ Bw,
    float* __restrict__ Cout,
    us* __restrict__ Qo, us* __restrict__ Ko, us* __restrict__ Vo,
    const float* __restrict__ b0, const float* __restrict__ b2, int ny, int total)
{
    __shared__ __align__(16) us AsB[3][12288];   // per buf: A [0,4096) + B [4096,12288)
    us* cbuf = &AsB[2][0];   // epilogue quarter scratch (24%3==0 -> buf 2 free at tile end)
    const int tid  = threadIdx.x;
    const int lane = tid & 63;
    const int wave = tid >> 6;
    const int wrr = wave >> 2;          // row half
    const int wcc = wave & 3;           // N band (64)
    const int lr = lane & 15;
    const int g  = lane >> 4;

    // XCD-chunked balanced decode: 8 spans, 64 blocks per span (NB=512)
    const int id  = blockIdx.x;
    const int xcd = id & 7;
    const int jb  = id >> 3;            // 0..63
    const int qs  = total >> 3, rs = total & 7;
    const int Ssp = xcd*qs + (xcd < rs ? xcd : rs);
    const int L   = qs + (xcd < rs ? 1 : 0);
    const int qb  = L >> 6, rb = L & 63;
    const int cnt = qb + (jb < rb ? 1 : 0);
    const int w0  = Ssp + jb*qb + (jb < rb ? jb : rb);
    if (cnt == 0) return;

    // staging: A 512 chunks (1/thread), B 1024 chunks (2/thread); 4 chunks/row,
    // source chunk swizzled cg = ch ^ ((row>>1)&3)
    int aoff, aldo, bofs[2], bldo[2];
    {
        int c = tid;
        int row = c >> 2, ch = c & 3;
        aoff = row*CDIM + ((ch ^ ((row >> 1) & 3))*8);
        aldo = c*8;
    }
    #pragma unroll
    for (int jj=0;jj<2;jj++){
        int c = tid + jj*512;
        int row = c >> 2, ch = c & 3;
        bofs[jj] = row*CDIM + ((ch ^ ((row >> 1) & 3))*8);
        bldo[jj] = 4096 + c*8;
    }

    const int S = cnt * 24;
    auto stageStep = [&](int x){
        int tt = x / 24, kt = x - tt*24;
        int ww = w0 + tt;
        int bx = ww / ny, by = ww - bx*ny;
        const us* pA = A  + (size_t)(bx*128)*CDIM;
        const us* pB = Bw + (size_t)(by*256)*CDIM;
        int buf = x % 3;
        gload16(pA + aoff + kt*32, &AsB[buf][aldo]);
        #pragma unroll
        for (int jj=0;jj<2;jj++) gload16(pB + bofs[jj] + kt*32, &AsB[buf][bldo[jj]]);
    };

    stageStep(0);
    if (S > 1) stageStep(1);
    int s = 0;

    const int co = 8*(g ^ ((lr >> 1) & 3));   // ds_read swizzled chunk offset

    #pragma unroll 1
    for (int tt = 0; tt < cnt; ++tt){
        const int w  = w0 + tt;
        const int bx = w / ny, by = w - bx*ny;
        const int m0 = bx*128, n0 = by*256;
        const int whc = (EPI == 0) ? (n0 / CDIM) : 0;
        float addf[4];
        const float sclf = (EPI == 0 && whc == 0) ? SCALE : 1.f;
        #pragma unroll
        for (int nt=0;nt<4;nt++){
            int n = n0 + wcc*64 + nt*16 + lr;
            if (EPI == 1) addf[nt] = b0[n];
            else {
                int hn = n - whc*CDIM;
                addf[nt] = (whc == 0) ? b0[hn] : (whc == 2 ? b2[hn] : 0.f);
            }
        }

        f32x4 acc[4][4];
        #pragma unroll
        for (int i=0;i<4;i++)
            #pragma unroll
            for (int jj=0;jj<4;jj++) acc[i][jj] = (f32x4){0.f,0.f,0.f,0.f};

        #pragma unroll 1
        for (int kt = 0; kt < 24; ++kt){
            if (s == S-1) asm volatile("s_waitcnt vmcnt(0)" ::: "memory");
            else          asm volatile("s_waitcnt vmcnt(3)" ::: "memory");
            __builtin_amdgcn_s_barrier();
            if (s + 2 < S) stageStep(s + 2);
            const us* la = &AsB[s % 3][0];
            const us* lb = &AsB[s % 3][4096];
            short8 af[4], bf[4];
            #pragma unroll
            for (int mt=0;mt<4;mt++)
                af[mt] = *(const short8*)&la[(wrr*64+mt*16+lr)*32 + co];
            #pragma unroll
            for (int nt=0;nt<4;nt++)
                bf[nt] = *(const short8*)&lb[(wcc*64+nt*16+lr)*32 + co];
            __builtin_amdgcn_s_setprio(1);
            #pragma unroll
            for (int mt=0;mt<4;mt++)
                #pragma unroll
                for (int nt=0;nt<4;nt++)
                    acc[mt][nt] = __builtin_amdgcn_mfma_f32_16x16x32_bf16(af[mt], bf[nt], acc[mt][nt], 0,0,0);
            __builtin_amdgcn_s_setprio(0);
            ++s;
        }

        LGKM0_BAR();   // buffer-2 reads consumed before cbuf reuse

        const us* outp = (EPI == 0) ? (whc == 0 ? Qo : (whc == 1 ? Ko : Vo)) : nullptr;
        #pragma unroll 1
        for (int ph = 0; ph < 4; ++ph){
            const int half  = ph & 1;       // col half of 128
            const int rhalf = ph >> 1;      // row half of 64
            if (wrr == rhalf && (wcc >> 1) == half){
                #pragma unroll
                for (int mt=0;mt<4;mt++)
                    #pragma unroll
                    for (int rr=0;rr<4;rr++){
                        int row = mt*16 + g*4 + rr;        // 0..63 within quarter
                        #pragma unroll
                        for (int nt=0;nt<4;nt++){
                            int col = (wcc & 1)*64 + nt*16 + lr;
                            cbuf[row*132 + col] = f2b((acc[mt][nt][rr] + addf[nt]) * sclf);
                        }
                    }
            }
            LGKM0_BAR();
            #pragma unroll
            for (int p=0;p<2;p++){
                int c = tid + p*512;
                int row = c >> 4, ch = c & 15;
                int m = m0 + rhalf*64 + row;
                if (m < MTOT){
                    short8 vv = *(const short8*)&cbuf[row*132 + ch*8];
                    int n = n0 + half*128 + ch*8;
                    if (EPI == 1){
                        float4 f0, f1;
                        f0.x = b2f((us)vv[0]); f0.y = b2f((us)vv[1]); f0.z = b2f((us)vv[2]); f0.w = b2f((us)vv[3]);
                        f1.x = b2f((us)vv[4]); f1.y = b2f((us)vv[5]); f1.z = b2f((us)vv[6]); f1.w = b2f((us)vv[7]);
                        *(float4*)&Cout[(size_t)m*CDIM + n]     = f0;
                        *(float4*)&Cout[(size_t)m*CDIM + n + 4] = f1;
                    } else {
                        int hn = n - whc*CDIM;
                        int h  = hn >> 6, d0 = hn & 63;
                        int bidx = m / NTOK;
                        int tok  = m - bidx*NTOK;
                        size_t off = ((size_t)((bidx*NH + h)*NTOK + tok))*HD + d0;
                        *(short8*)((us*)outp + off) = vv;
                    }
                }
            }
            LGKM0_BAR();
        }
    }
}

// ---------------- fused attention (identical to R14) ----------------
__global__ __launch_bounds__(256) void attn_kernel(
    const us* __restrict__ Q,
    const us* __restrict__ K,
    const us* __restrict__ V,
    const float* __restrict__ biasT,
    us* __restrict__ Ao)
{
    __shared__ us Vt[64][232];
    __shared__ us Ps[4][16][232];
    const int bh = blockIdx.x;
    const int b = bh / NH;
    const int h = bh - b*NH;
    const us* Qh = Q + (size_t)bh*NTOK*HD;
    const us* Kh = K + (size_t)bh*NTOK*HD;
    const us* Vh = V + (size_t)bh*NTOK*HD;
    const float* bT = biasT + (size_t)h*BTP*BTP;
    const int tid = threadIdx.x, lane = tid & 63, wave = tid >> 6;
    const int lr = lane & 15, g = lane >> 4, ko = g*8;

    for (int i = tid; i < 64*232/2; i += 256) ((uint32_t*)Vt)[i] = 0;
    __syncthreads();
    {
        int d0 = (tid & 7) * 8;
        for (int t = tid >> 3; t < NTOK; t += 32){
            short8 v = *(const short8*)&Vh[t*HD + d0];
            #pragma unroll
            for (int j=0;j<8;j++) Vt[d0+j][t] = (us)v[j];
        }
    }
    __syncthreads();

    for (int s = wave; s < 13; s += 4){
        int qrow = s*16 + lr; qrow = qrow > 196 ? 196 : qrow;
        short8 qa0 = *(const short8*)&Qh[qrow*HD + ko];
        short8 qa1 = *(const short8*)&Qh[qrow*HD + 32 + ko];
        f32x4 S[13];
        #pragma unroll
        for (int t=0;t<13;t++){
            int kc = t*16 + lr; kc = kc > 196 ? 196 : kc;
            short8 kb0 = *(const short8*)&Kh[kc*HD + ko];
            short8 kb1 = *(const short8*)&Kh[kc*HD + 32 + ko];
            f32x4 a = (f32x4){0.f,0.f,0.f,0.f};
            a = __builtin_amdgcn_mfma_f32_16x16x32_bf16(qa0, kb0, a, 0,0,0);
            a = __builtin_amdgcn_mfma_f32_16x16x32_bf16(qa1, kb1, a, 0,0,0);
            S[t] = a;
        }
        float rmax[4] = {-3e38f,-3e38f,-3e38f,-3e38f};
        #pragma unroll
        for (int t=0;t<13;t++){
            int col = t*16 + lr;
            bool cok = col < NTOK;
            float4 b4 = *(const float4*)&bT[(size_t)col*BTP + s*16 + g*4];
            #pragma unroll
            for (int r=0;r<4;r++){
                float xv = S[t][r] + ((const float*)&b4)[r];
                xv = cok ? xv : -1e30f;
                S[t][r] = xv;
                rmax[r] = fmaxf(rmax[r], xv);
            }
        }
        #pragma unroll
        for (int r=0;r<4;r++)
            #pragma unroll
            for (int msk=1; msk<16; msk<<=1)
                rmax[r] = fmaxf(rmax[r], __shfl_xor(rmax[r], msk));
        float rsum[4] = {0.f,0.f,0.f,0.f};
        #pragma unroll
        for (int t=0;t<13;t++)
            #pragma unroll
            for (int r=0;r<4;r++){
                float e = __expf(S[t][r] - rmax[r]);
                S[t][r] = e;
                rsum[r] += e;
            }
        #pragma unroll
        for (int r=0;r<4;r++){
            #pragma unroll
            for (int msk=1; msk<16; msk<<=1)
                rsum[r] += __shfl_xor(rsum[r], msk);
            rsum[r] = 1.f / rsum[r];
        }
        #pragma unroll
        for (int t=0;t<13;t++)
            #pragma unroll
            for (int r=0;r<4;r++)
                Ps[wave][g*4+r][t*16+lr] = f2b(S[t][r] * rsum[r]);
        #pragma unroll
        for (int r=0;r<4;r++) Ps[wave][g*4+r][208+lr] = 0;
        asm volatile("s_waitcnt lgkmcnt(0)" ::: "memory");
        f32x4 pv[4];
        #pragma unroll
        for (int nt=0;nt<4;nt++) pv[nt] = (f32x4){0.f,0.f,0.f,0.f};
        #pragma unroll
        for (int ks=0; ks<7; ks++){
            int k0 = ks*32 + ko;
            short8 pa = *(const short8*)&Ps[wave][lr][k0];
            #pragma unroll
            for (int nt=0;nt<4;nt++){
                short8 vb = *(const short8*)&Vt[nt*16+lr][k0];
                pv[nt] = __builtin_amdgcn_mfma_f32_16x16x32_bf16(pa, vb, pv[nt], 0,0,0);
            }
        }
        #pragma unroll
        for (int nt=0;nt<4;nt++)
            #pragma unroll
            for (int r=0;r<4;r++){
                int tok = s*16 + g*4 + r;
                if (tok < NTOK)
                    Ao[(size_t)(b*NTOK + tok)*CDIM + h*HD + nt*16 + lr] = f2b(pv[nt][r]);
            }
    }
}

extern "C" void kernel_launch(void* const* d_in, const int* in_sizes, int n_in,
                              void* d_out, int out_size, void* d_ws, size_t ws_size,
                              hipStream_t stream)
{
    const float* x        = (const float*)d_in[0];
    const float* qkv_w    = (const float*)d_in[1];
    const float* q_bias   = (const float*)d_in[2];
    const float* v_bias   = (const float*)d_in[3];
    const float* rel_tab  = (const float*)d_in[4];
    const float* proj_w   = (const float*)d_in[5];
    const float* proj_b   = (const float*)d_in[6];
    const int*   rel_idx  = (const int*)d_in[7];
    float* out = (float*)d_out;

    char* w = (char*)d_ws;
    us* xb    = (us*)w; w += (size_t)MPAD*CDIM*2;
    us* wqkv  = (us*)w; w += (size_t)3*CDIM*CDIM*2;
    us* wproj = (us*)w; w += (size_t)CDIM*CDIM*2;
    us* Qb    = (us*)w; w += (size_t)BB*NH*NTOK*HD*2;
    us* Kb    = (us*)w; w += (size_t)BB*NH*NTOK*HD*2;
    us* Vb    = (us*)w; w += (size_t)BB*NH*NTOK*HD*2;
    float* biasT = (float*)w; w += (size_t)NH*BTP*BTP*4;
    us* aob   = (us*)w; w += (size_t)MPAD*CDIM*2;

    prep_kernel<<<2048, 256, 0, stream>>>(x, qkv_w, proj_w, rel_idx, rel_tab,
                                          xb, wqkv, wproj, biasT);

    // QKV: 99 bx x 9 by = 891 tiles of 128x256, XCD-chunked over 512 blocks (2/CU)
    pgemm6_kernel<0><<<512, 512, 0, stream>>>(xb, wqkv, nullptr, Qb, Kb, Vb, q_bias, v_bias, 9, 891);
    attn_kernel<<<BB*NH, 256, 0, stream>>>(Qb, Kb, Vb, biasT, aob);
    // proj: 99 bx x 3 by = 297 tiles of 128x256 over 512 blocks (1 tile max/block)
    pgemm6_kernel<1><<<512, 512, 0, stream>>>(aob, wproj, out, nullptr, nullptr, nullptr, proj_b, nullptr, 3, 297);
}

// Round 19
// 152.380 us; speedup vs baseline: 1.0160x; 1.0160x over previous
//
#include <hip/hip_runtime.h>
#include <stdint.h>

#define NTOK 197
#define HD 64
#define NH 12
#define CDIM 768
#define BB 64
#define MTOT (BB*NTOK)      /* 12608 */
#define MPAD 12672          /* 99*128 */
#define SCALE 0.125f
#define BTP 208             /* biasT padded dim */

typedef __attribute__((ext_vector_type(8))) short short8;
typedef __attribute__((ext_vector_type(4))) float f32x4;
typedef unsigned short us;

__device__ __forceinline__ us f2b(float f){
    union { float f; uint32_t u; } v; v.f = f;
    uint32_t u = v.u;
    uint32_t r = u + 0x7fffu + ((u >> 16) & 1u);
    return (us)(r >> 16);
}

__device__ __forceinline__ float b2f(us b){
    union { uint32_t u; float f; } v; v.u = ((uint32_t)b) << 16;
    return v.f;
}

__device__ __forceinline__ void gload16(const us* g, us* l){
    __builtin_amdgcn_global_load_lds((const __attribute__((address_space(1))) void*)g,
                                     (__attribute__((address_space(3))) void*)l, 16, 0, 0);
}

#define LGKM0_BAR() do{ asm volatile("s_waitcnt lgkmcnt(0)" ::: "memory"); \
                        __builtin_amdgcn_s_barrier(); }while(0)

// ---------------- fused prep (identical to R14) ----------------
__device__ __forceinline__ void cvt4(const float* in, us* out, int i){
    float4 v = ((const float4*)in)[i];
    ushort4 o;
    o.x = f2b(v.x); o.y = f2b(v.y); o.z = f2b(v.z); o.w = f2b(v.w);
    ((ushort4*)out)[i] = o;
}

__global__ void prep_kernel(const float* __restrict__ x, const float* __restrict__ qkv_w,
                            const float* __restrict__ proj_w,
                            const int* __restrict__ rel_index, const float* __restrict__ rel_table,
                            us* __restrict__ xb, us* __restrict__ wqkv, us* __restrict__ wproj,
                            float* __restrict__ biasT)
{
    const int N1 = MTOT*CDIM/4;
    const int N2 = 3*CDIM*CDIM/4;
    const int N3 = CDIM*CDIM/4;
    const int N4 = BTP*BTP;
    const int total = N1+N2+N3+N4;
    for (int i = blockIdx.x*blockDim.x + threadIdx.x; i < total; i += gridDim.x*blockDim.x){
        if (i < N1) cvt4(x, xb, i);
        else if (i < N1+N2) cvt4(qkv_w, wqkv, i-N1);
        else if (i < N1+N2+N3) cvt4(proj_w, wproj, i-N1-N2);
        else {
            int t = i - N1 - N2 - N3;
            int col = t / BTP, row = t - col*BTP;
            if (row < NTOK && col < NTOK){
                int idx = rel_index[row*NTOK + col];
                #pragma unroll
                for (int h = 0; h < NH; ++h)
                    biasT[((size_t)h*BTP + col)*BTP + row] = rel_table[idx*NH + h];
            } else {
                #pragma unroll
                for (int h = 0; h < NH; ++h)
                    biasT[((size_t)h*BTP + col)*BTP + row] = 0.f;
            }
        }
    }
}

// ====== QKV: persistent 8-wave GEMM, BM=128, BN=256, BK=32, 3-buffer rotation,
//        single barrier/step, counted vmcnt(3), 72KB LDS -> 2 blocks/CU (R17) ======
__global__ __launch_bounds__(512,2) void pgemm6_kernel(
    const us* __restrict__ A, const us* __restrict__ Bw,
    us* __restrict__ Qo, us* __restrict__ Ko, us* __restrict__ Vo,
    const float* __restrict__ b0, const float* __restrict__ b2, int ny, int total)
{
    __shared__ __align__(16) us AsB[3][12288];   // per buf: A [0,4096) + B [4096,12288)
    us* cbuf = &AsB[2][0];   // epilogue quarter scratch (24%3==0 -> buf 2 free at tile end)
    const int tid  = threadIdx.x;
    const int lane = tid & 63;
    const int wave = tid >> 6;
    const int wrr = wave >> 2;          // row half
    const int wcc = wave & 3;           // N band (64)
    const int lr = lane & 15;
    const int g  = lane >> 4;

    // XCD-chunked balanced decode: 8 spans, 64 blocks per span
    const int id  = blockIdx.x;
    const int xcd = id & 7;
    const int jb  = id >> 3;            // 0..63
    const int qs  = total >> 3, rs = total & 7;
    const int Ssp = xcd*qs + (xcd < rs ? xcd : rs);
    const int L   = qs + (xcd < rs ? 1 : 0);
    const int qb  = L >> 6, rb = L & 63;
    const int cnt = qb + (jb < rb ? 1 : 0);
    const int w0  = Ssp + jb*qb + (jb < rb ? jb : rb);
    if (cnt == 0) return;

    int aoff, aldo, bofs[2], bldo[2];
    {
        int c = tid;
        int row = c >> 2, ch = c & 3;
        aoff = row*CDIM + ((ch ^ ((row >> 1) & 3))*8);
        aldo = c*8;
    }
    #pragma unroll
    for (int jj=0;jj<2;jj++){
        int c = tid + jj*512;
        int row = c >> 2, ch = c & 3;
        bofs[jj] = row*CDIM + ((ch ^ ((row >> 1) & 3))*8);
        bldo[jj] = 4096 + c*8;
    }

    const int S = cnt * 24;
    auto stageStep = [&](int x){
        int tt = x / 24, kt = x - tt*24;
        int ww = w0 + tt;
        int bx = ww / ny, by = ww - bx*ny;
        const us* pA = A  + (size_t)(bx*128)*CDIM;
        const us* pB = Bw + (size_t)(by*256)*CDIM;
        int buf = x % 3;
        gload16(pA + aoff + kt*32, &AsB[buf][aldo]);
        #pragma unroll
        for (int jj=0;jj<2;jj++) gload16(pB + bofs[jj] + kt*32, &AsB[buf][bldo[jj]]);
    };

    stageStep(0);
    if (S > 1) stageStep(1);
    int s = 0;

    const int co = 8*(g ^ ((lr >> 1) & 3));   // ds_read swizzled chunk offset

    #pragma unroll 1
    for (int tt = 0; tt < cnt; ++tt){
        const int w  = w0 + tt;
        const int bx = w / ny, by = w - bx*ny;
        const int m0 = bx*128, n0 = by*256;
        const int whc = n0 / CDIM;
        float addf[4];
        const float sclf = (whc == 0) ? SCALE : 1.f;
        #pragma unroll
        for (int nt=0;nt<4;nt++){
            int n = n0 + wcc*64 + nt*16 + lr;
            int hn = n - whc*CDIM;
            addf[nt] = (whc == 0) ? b0[hn] : (whc == 2 ? b2[hn] : 0.f);
        }

        f32x4 acc[4][4];
        #pragma unroll
        for (int i=0;i<4;i++)
            #pragma unroll
            for (int jj=0;jj<4;jj++) acc[i][jj] = (f32x4){0.f,0.f,0.f,0.f};

        #pragma unroll 1
        for (int kt = 0; kt < 24; ++kt){
            if (s == S-1) asm volatile("s_waitcnt vmcnt(0)" ::: "memory");
            else          asm volatile("s_waitcnt vmcnt(3)" ::: "memory");
            __builtin_amdgcn_s_barrier();
            if (s + 2 < S) stageStep(s + 2);
            const us* la = &AsB[s % 3][0];
            const us* lb = &AsB[s % 3][4096];
            short8 af[4], bf[4];
            #pragma unroll
            for (int mt=0;mt<4;mt++)
                af[mt] = *(const short8*)&la[(wrr*64+mt*16+lr)*32 + co];
            #pragma unroll
            for (int nt=0;nt<4;nt++)
                bf[nt] = *(const short8*)&lb[(wcc*64+nt*16+lr)*32 + co];
            __builtin_amdgcn_s_setprio(1);
            #pragma unroll
            for (int mt=0;mt<4;mt++)
                #pragma unroll
                for (int nt=0;nt<4;nt++)
                    acc[mt][nt] = __builtin_amdgcn_mfma_f32_16x16x32_bf16(af[mt], bf[nt], acc[mt][nt], 0,0,0);
            __builtin_amdgcn_s_setprio(0);
            ++s;
        }

        LGKM0_BAR();   // buffer-2 reads consumed before cbuf reuse

        const us* outp = (whc == 0 ? Qo : (whc == 1 ? Ko : Vo));
        #pragma unroll 1
        for (int ph = 0; ph < 4; ++ph){
            const int half  = ph & 1;       // col half of 128
            const int rhalf = ph >> 1;      // row half of 64
            if (wrr == rhalf && (wcc >> 1) == half){
                #pragma unroll
                for (int mt=0;mt<4;mt++)
                    #pragma unroll
                    for (int rr=0;rr<4;rr++){
                        int row = mt*16 + g*4 + rr;        // 0..63 within quarter
                        #pragma unroll
                        for (int nt=0;nt<4;nt++){
                            int col = (wcc & 1)*64 + nt*16 + lr;
                            cbuf[row*132 + col] = f2b((acc[mt][nt][rr] + addf[nt]) * sclf);
                        }
                    }
            }
            LGKM0_BAR();
            #pragma unroll
            for (int p=0;p<2;p++){
                int c = tid + p*512;
                int row = c >> 4, ch = c & 15;
                int m = m0 + rhalf*64 + row;
                if (m < MTOT){
                    short8 vv = *(const short8*)&cbuf[row*132 + ch*8];
                    int n = n0 + half*128 + ch*8;
                    int hn = n - whc*CDIM;
                    int h  = hn >> 6, d0 = hn & 63;
                    int bidx = m / NTOK;
                    int tok  = m - bidx*NTOK;
                    size_t off = ((size_t)((bidx*NH + h)*NTOK + tok))*HD + d0;
                    *(short8*)((us*)outp + off) = vv;
                }
            }
            LGKM0_BAR();
        }
    }
}

// ====== proj: R8/R17-style 256-thread GEMM, BM=BN=BK=128, single-buffer, 1 tile/block ======
__global__ __launch_bounds__(256) void proj_gemm_kernel(
    const us* __restrict__ A, const us* __restrict__ Bw,
    float* __restrict__ Cout, const float* __restrict__ b0, int ny)
{
    __shared__ __align__(16) us lds[32768];
    us* As = lds;
    us* Bs = lds + 16384;
    const int tid  = threadIdx.x;
    const int lane = tid & 63;
    const int wave = tid >> 6;
    const int wr = wave >> 1, wc = wave & 1;
    const int lr = lane & 15;
    const int g  = lane >> 4;

    const int NB   = gridDim.x;
    const int base = NB >> 3;
    const int rem  = NB & 7;
    const int id   = blockIdx.x;
    const int xcd  = id & 7;
    const int qq   = id >> 3;
    const int start = (xcd < rem) ? xcd*(base+1) : rem*(base+1) + (xcd-rem)*base;
    const int w    = start + qq;
    const int bx   = w / ny;
    const int by   = w - bx*ny;
    const int m0 = bx * 128;
    const int n0 = by * 128;
    const int NT = CDIM / 128;

    const int row0 = tid >> 4;
    const int cg   = (tid & 15) ^ row0;

    float addf[4];
    #pragma unroll
    for (int nt=0;nt<4;nt++) addf[nt] = b0[n0 + wc*64 + nt*16 + lr];

    f32x4 acc[4][4];
    #pragma unroll
    for (int i=0;i<4;i++)
        #pragma unroll
        for (int j=0;j<4;j++) acc[i][j] = (f32x4){0.f,0.f,0.f,0.f};

    const us* gA = A  + (size_t)(m0 + row0)*CDIM + cg*8;
    const us* gB = Bw + (size_t)(n0 + row0)*CDIM + cg*8;

    #pragma unroll 1
    for (int kt = 0; kt < NT; ++kt){
        __syncthreads();
        #pragma unroll
        for (int j=0;j<8;j++){
            gload16(gA + (size_t)j*16*CDIM + kt*128, As + tid*8 + j*2048);
            gload16(gB + (size_t)j*16*CDIM + kt*128, Bs + tid*8 + j*2048);
        }
        __syncthreads();
        #pragma unroll
        for (int kk=0; kk<4; ++kk){
            const int co = 8*((kk*4 + g) ^ lr);
            short8 af[4], bf[4];
            #pragma unroll
            for (int mt=0;mt<4;mt++)
                af[mt] = *(const short8*)&As[(wr*64+mt*16+lr)*128 + co];
            #pragma unroll
            for (int nt=0;nt<4;nt++)
                bf[nt] = *(const short8*)&Bs[(wc*64+nt*16+lr)*128 + co];
            __builtin_amdgcn_s_setprio(1);
            #pragma unroll
            for (int mt=0;mt<4;mt++)
                #pragma unroll
                for (int nt=0;nt<4;nt++)
                    acc[mt][nt] = __builtin_amdgcn_mfma_f32_16x16x32_bf16(af[mt], bf[nt], acc[mt][nt], 0,0,0);
            __builtin_amdgcn_s_setprio(0);
        }
    }

    __syncthreads();
    #pragma unroll
    for (int mt=0;mt<4;mt++)
        #pragma unroll
        for (int r=0;r<4;r++){
            int row = wr*64 + mt*16 + g*4 + r;
            #pragma unroll
            for (int nt=0;nt<4;nt++){
                int col = wc*64 + nt*16 + lr;
                lds[row*132 + col] = f2b(acc[mt][nt][r] + addf[nt]);
            }
        }
    __syncthreads();
    #pragma unroll
    for (int j=0;j<8;j++){
        int c2  = tid + j*256;
        int row = c2 >> 4;
        int ch  = c2 & 15;
        int m = m0 + row;
        if (m >= MTOT) continue;
        short8 vv = *(const short8*)&lds[row*132 + ch*8];
        int n = n0 + ch*8;
        float4 f0, f1;
        f0.x = b2f((us)vv[0]); f0.y = b2f((us)vv[1]); f0.z = b2f((us)vv[2]); f0.w = b2f((us)vv[3]);
        f1.x = b2f((us)vv[4]); f1.y = b2f((us)vv[5]); f1.z = b2f((us)vv[6]); f1.w = b2f((us)vv[7]);
        *(float4*)&Cout[(size_t)m*CDIM + n]     = f0;
        *(float4*)&Cout[(size_t)m*CDIM + n + 4] = f1;
    }
}

// ---------------- fused attention: vectorized output stores via Ps bounce ----------------
__global__ __launch_bounds__(256) void attn_kernel(
    const us* __restrict__ Q,
    const us* __restrict__ K,
    const us* __restrict__ V,
    const float* __restrict__ biasT,
    us* __restrict__ Ao)
{
    __shared__ us Vt[64][232];
    __shared__ us Ps[4][16][232];
    const int bh = blockIdx.x;
    const int b = bh / NH;
    const int h = bh - b*NH;
    const us* Qh = Q + (size_t)bh*NTOK*HD;
    const us* Kh = K + (size_t)bh*NTOK*HD;
    const us* Vh = V + (size_t)bh*NTOK*HD;
    const float* bT = biasT + (size_t)h*BTP*BTP;
    const int tid = threadIdx.x, lane = tid & 63, wave = tid >> 6;
    const int lr = lane & 15, g = lane >> 4, ko = g*8;

    for (int i = tid; i < 64*232/2; i += 256) ((uint32_t*)Vt)[i] = 0;
    __syncthreads();
    {
        int d0 = (tid & 7) * 8;
        for (int t = tid >> 3; t < NTOK; t += 32){
            short8 v = *(const short8*)&Vh[t*HD + d0];
            #pragma unroll
            for (int j=0;j<8;j++) Vt[d0+j][t] = (us)v[j];
        }
    }
    __syncthreads();

    for (int s = wave; s < 13; s += 4){
        int qrow = s*16 + lr; qrow = qrow > 196 ? 196 : qrow;
        short8 qa0 = *(const short8*)&Qh[qrow*HD + ko];
        short8 qa1 = *(const short8*)&Qh[qrow*HD + 32 + ko];
        f32x4 S[13];
        #pragma unroll
        for (int t=0;t<13;t++){
            int kc = t*16 + lr; kc = kc > 196 ? 196 : kc;
            short8 kb0 = *(const short8*)&Kh[kc*HD + ko];
            short8 kb1 = *(const short8*)&Kh[kc*HD + 32 + ko];
            f32x4 a = (f32x4){0.f,0.f,0.f,0.f};
            a = __builtin_amdgcn_mfma_f32_16x16x32_bf16(qa0, kb0, a, 0,0,0);
            a = __builtin_amdgcn_mfma_f32_16x16x32_bf16(qa1, kb1, a, 0,0,0);
            S[t] = a;
        }
        float rmax[4] = {-3e38f,-3e38f,-3e38f,-3e38f};
        #pragma unroll
        for (int t=0;t<13;t++){
            int col = t*16 + lr;
            bool cok = col < NTOK;
            float4 b4 = *(const float4*)&bT[(size_t)col*BTP + s*16 + g*4];
            #pragma unroll
            for (int r=0;r<4;r++){
                float xv = S[t][r] + ((const float*)&b4)[r];
                xv = cok ? xv : -1e30f;
                S[t][r] = xv;
                rmax[r] = fmaxf(rmax[r], xv);
            }
        }
        #pragma unroll
        for (int r=0;r<4;r++)
            #pragma unroll
            for (int msk=1; msk<16; msk<<=1)
                rmax[r] = fmaxf(rmax[r], __shfl_xor(rmax[r], msk));
        float rsum[4] = {0.f,0.f,0.f,0.f};
        #pragma unroll
        for (int t=0;t<13;t++)
            #pragma unroll
            for (int r=0;r<4;r++){
                float e = __expf(S[t][r] - rmax[r]);
                S[t][r] = e;
                rsum[r] += e;
            }
        #pragma unroll
        for (int r=0;r<4;r++){
            #pragma unroll
            for (int msk=1; msk<16; msk<<=1)
                rsum[r] += __shfl_xor(rsum[r], msk);
            rsum[r] = 1.f / rsum[r];
        }
        #pragma unroll
        for (int t=0;t<13;t++)
            #pragma unroll
            for (int r=0;r<4;r++)
                Ps[wave][g*4+r][t*16+lr] = f2b(S[t][r] * rsum[r]);
        #pragma unroll
        for (int r=0;r<4;r++) Ps[wave][g*4+r][208+lr] = 0;
        asm volatile("s_waitcnt lgkmcnt(0)" ::: "memory");
        f32x4 pv[4];
        #pragma unroll
        for (int nt=0;nt<4;nt++) pv[nt] = (f32x4){0.f,0.f,0.f,0.f};
        #pragma unroll
        for (int ks=0; ks<7; ks++){
            int k0 = ks*32 + ko;
            short8 pa = *(const short8*)&Ps[wave][lr][k0];
            #pragma unroll
            for (int nt=0;nt<4;nt++){
                short8 vb = *(const short8*)&Vt[nt*16+lr][k0];
                pv[nt] = __builtin_amdgcn_mfma_f32_16x16x32_bf16(pa, vb, pv[nt], 0,0,0);
            }
        }
        // ---- vectorized output: bounce pv through this wave's Ps strip ----
        // (Ps reads for PV are consumed via the pv data-dependence; wave-local, no barrier)
        #pragma unroll
        for (int nt=0;nt<4;nt++)
            #pragma unroll
            for (int r=0;r<4;r++)
                Ps[wave][g*4+r][nt*16+lr] = f2b(pv[nt][r]);
        asm volatile("s_waitcnt lgkmcnt(0)" ::: "memory");
        #pragma unroll
        for (int p=0;p<2;p++){
            int c = lane + p*64;
            int row = c >> 3, ch = c & 7;      // 16 rows x 8 chunks of 8 cols
            int tok = s*16 + row;
            if (tok < NTOK){
                short8 vv = *(const short8*)&Ps[wave][row][ch*8];
                *(short8*)&Ao[(size_t)(b*NTOK + tok)*CDIM + h*HD + ch*8] = vv;
            }
        }
    }
}

extern "C" void kernel_launch(void* const* d_in, const int* in_sizes, int n_in,
                              void* d_out, int out_size, void* d_ws, size_t ws_size,
                              hipStream_t stream)
{
    const float* x        = (const float*)d_in[0];
    const float* qkv_w    = (const float*)d_in[1];
    const float* q_bias   = (const float*)d_in[2];
    const float* v_bias   = (const float*)d_in[3];
    const float* rel_tab  = (const float*)d_in[4];
    const float* proj_w   = (const float*)d_in[5];
    const float* proj_b   = (const float*)d_in[6];
    const int*   rel_idx  = (const int*)d_in[7];
    float* out = (float*)d_out;

    char* w = (char*)d_ws;
    us* xb    = (us*)w; w += (size_t)MPAD*CDIM*2;
    us* wqkv  = (us*)w; w += (size_t)3*CDIM*CDIM*2;
    us* wproj = (us*)w; w += (size_t)CDIM*CDIM*2;
    us* Qb    = (us*)w; w += (size_t)BB*NH*NTOK*HD*2;
    us* Kb    = (us*)w; w += (size_t)BB*NH*NTOK*HD*2;
    us* Vb    = (us*)w; w += (size_t)BB*NH*NTOK*HD*2;
    float* biasT = (float*)w; w += (size_t)NH*BTP*BTP*4;
    us* aob   = (us*)w; w += (size_t)MPAD*CDIM*2;

    prep_kernel<<<2048, 256, 0, stream>>>(x, qkv_w, proj_w, rel_idx, rel_tab,
                                          xb, wqkv, wproj, biasT);

    // QKV: 99 bx x 9 by = 891 tiles of 128x256, XCD-chunked over 512 blocks (2/CU)
    pgemm6_kernel<<<512, 512, 0, stream>>>(xb, wqkv, Qb, Kb, Vb, q_bias, v_bias, 9, 891);
    attn_kernel<<<BB*NH, 256, 0, stream>>>(Qb, Kb, Vb, biasT, aob);
    // proj: 99 x 6 = 594 tiles of 128x128, 1 per block (R17 arrangement)
    proj_gemm_kernel<<<594, 256, 0, stream>>>(aob, wproj, out, proj_b, 6);
}